// Round 10
// baseline (373.261 us; speedup 1.0000x reference)
//
#include <hip/hip_runtime.h>

// -------------------- helpers --------------------
static __device__ __forceinline__ float4 ld4(const float* p) { return *(const float4*)p; }
static __device__ __forceinline__ float b2f(unsigned short u) {
    return __uint_as_float((unsigned)u << 16);
}
static __device__ __forceinline__ float b2f_lo(unsigned u) { return __uint_as_float(u << 16); }
static __device__ __forceinline__ float b2f_hi(unsigned u) { return __uint_as_float(u & 0xFFFF0000u); }
static __device__ __forceinline__ unsigned short f2b(float f) {   // round-to-nearest-even
    unsigned x = __float_as_uint(f);
    return (unsigned short)((x + 0x7FFFu + ((x >> 16) & 1u)) >> 16);
}

#define NPB 256              // nodes per bin (pow2: ld = d & 255, bin = d >> 8)
#define CAPE 5120            // per-bin edge capacity (mean ~4092, wide slack)

// math: layer1  q[d] = dinv_d * relu( dinv_d*(g0[d] + sum_e w_e*g0[s]) + b1 ),  g0 = dinv (.) (x@W1)
//       layer2  [mu|lv][d] = ( dinv_d*(q[d] + sum_e w_e*q[s]) ) @ [Wmu|Wlv] + [bmu|blv]
// CSR stores (src, raw ew).

// ==================== fused kernel 1: gemm1 (x@W1 -> h0, unscaled) + edge binning ============
__global__ __launch_bounds__(256) void k_fused1(const float* __restrict__ A,
                                                const float* __restrict__ W0,
                                                unsigned short* __restrict__ hout,
                                                const int* __restrict__ src,
                                                const int* __restrict__ dst,
                                                const float* __restrict__ ew,
                                                int* __restrict__ bin_cnt,
                                                unsigned long long* __restrict__ ebuf,
                                                int n, int E, int gb, int NB) {
    __shared__ float Ws[64 * 64];     // 16 KB
    __shared__ float Xs[64 * 64];     // 16 KB
    __shared__ int hist[512];
    __shared__ int hbase[512];
    int tid = threadIdx.x;

    if ((int)blockIdx.x < gb) {
        int row0 = blockIdx.x * 64;
        int c0 = (tid & 15) * 4;
        int r0 = (tid >> 4) * 4;
        float4 acc[4] = {};
        #pragma unroll
        for (int p = 0; p < 2; p++) {
            for (int j = tid; j < 1024; j += 256)
                *(float4*)&Ws[j * 4] = ld4(W0 + p * 4096 + j * 4);
            for (int j = tid; j < 1024; j += 256) {
                int r = j >> 4, kc = j & 15;
                int grow = row0 + r;
                float4 v = make_float4(0.f, 0.f, 0.f, 0.f);
                if (grow < n) v = ld4(A + (size_t)grow * 128 + p * 64 + kc * 4);
                *(float4*)&Xs[r * 64 + kc * 4] = v;
            }
            __syncthreads();
            #pragma unroll 4
            for (int kk = 0; kk < 64; kk += 4) {
                float4 w0 = ld4(&Ws[(kk + 0) * 64 + c0]);
                float4 w1 = ld4(&Ws[(kk + 1) * 64 + c0]);
                float4 w2 = ld4(&Ws[(kk + 2) * 64 + c0]);
                float4 w3 = ld4(&Ws[(kk + 3) * 64 + c0]);
                #pragma unroll
                for (int i = 0; i < 4; i++) {
                    float4 a = ld4(&Xs[(r0 + i) * 64 + kk]);
                    acc[i].x = fmaf(a.x, w0.x, fmaf(a.y, w1.x, fmaf(a.z, w2.x, fmaf(a.w, w3.x, acc[i].x))));
                    acc[i].y = fmaf(a.x, w0.y, fmaf(a.y, w1.y, fmaf(a.z, w2.y, fmaf(a.w, w3.y, acc[i].y))));
                    acc[i].z = fmaf(a.x, w0.z, fmaf(a.y, w1.z, fmaf(a.z, w2.z, fmaf(a.w, w3.z, acc[i].z))));
                    acc[i].w = fmaf(a.x, w0.w, fmaf(a.y, w1.w, fmaf(a.z, w2.w, fmaf(a.w, w3.w, acc[i].w))));
                }
            }
            __syncthreads();
        }
        #pragma unroll
        for (int i = 0; i < 4; i++) {
            int grow = row0 + r0 + i;
            if (grow < n) {
                ushort4 u = make_ushort4(f2b(acc[i].x), f2b(acc[i].y), f2b(acc[i].z), f2b(acc[i].w));
                *(ushort4*)&hout[(size_t)grow * 64 + c0] = u;
            }
        }
    } else {
        for (int j = tid; j < NB; j += 256) hist[j] = 0;
        __syncthreads();
        int e0 = ((int)blockIdx.x - gb) * 4096;
        unsigned long long pk[16]; int bb[16]; int loc[16];
        #pragma unroll
        for (int j = 0; j < 16; j++) {
            int e = e0 + j * 256 + tid;
            if (e < E) {
                int s = src[e];
                int d = dst[e];
                float w = ew[e];
                bb[j] = d >> 8;
                pk[j] = ((unsigned long long)__float_as_uint(w) << 32) |
                        (unsigned)((d & (NPB - 1)) << 17) | (unsigned)s;
                loc[j] = atomicAdd(&hist[bb[j]], 1);
            } else bb[j] = -1;
        }
        __syncthreads();
        for (int j = tid; j < NB; j += 256) hbase[j] = atomicAdd(&bin_cnt[j], hist[j]);
        __syncthreads();
        #pragma unroll
        for (int j = 0; j < 16; j++) {
            if (bb[j] >= 0)
                ebuf[(size_t)bb[j] * CAPE + hbase[bb[j]] + loc[j]] = pk[j];
        }
    }
}

// ==================== pass 2: per-bin LDS-resident count+scan+scatter ====================
__global__ __launch_bounds__(512) void k_csr_build(const unsigned long long* __restrict__ ebuf,
                                                   const int* __restrict__ bin_cnt,
                                                   int2* __restrict__ rowcnt,
                                                   float* __restrict__ dinv,
                                                   unsigned long long* __restrict__ csr,
                                                   int n) {
    __shared__ unsigned long long eL[CAPE];   // 40 KB
    __shared__ unsigned cntL[NPB];
    __shared__ unsigned ewsL[NPB];
    __shared__ unsigned fillL[NPB];
    __shared__ int scanL[512];
    __shared__ int rowL[NPB];
    __shared__ int binbase_s;
    int b = blockIdx.x;
    int tid = threadIdx.x;
    if (tid < NPB) { cntL[tid] = 0; ewsL[tid] = 0; fillL[tid] = 0; }
    scanL[tid] = (tid < b) ? bin_cnt[tid] : 0;
    __syncthreads();
    int m = bin_cnt[b];
    const unsigned long long* eb = ebuf + (size_t)b * CAPE;
    for (int i = tid; i < m; i += 512) {
        unsigned long long pk = eb[i];
        eL[i] = pk;
        int ld = (int)((pk >> 17) & (NPB - 1));
        float w = __uint_as_float((unsigned)(pk >> 32));
        atomicAdd(&cntL[ld], 1u);
        atomicAdd(&ewsL[ld], (unsigned)(w * 16777216.0f));   // 2^24 fixed point
    }
    __syncthreads();
    #pragma unroll
    for (int off = 256; off > 0; off >>= 1) {
        if (tid < off) scanL[tid] += scanL[tid + off];
        __syncthreads();
    }
    if (tid == 0) binbase_s = scanL[0];
    __syncthreads();
    int v = (tid < NPB) ? (int)cntL[tid] : 0;
    scanL[tid] = v;
    __syncthreads();
    #pragma unroll
    for (int off = 1; off < 512; off <<= 1) {
        int t = (tid >= off) ? scanL[tid - off] : 0;
        __syncthreads();
        scanL[tid] += t;
        __syncthreads();
    }
    if (tid < NPB) {
        int rp = binbase_s + scanL[tid] - v;
        rowL[tid] = rp;
        int node = b * NPB + tid;
        if (node < n) {
            rowcnt[node] = make_int2(rp, v);
            dinv[node] = rsqrtf(1.0f + (float)ewsL[tid] * (1.0f / 16777216.0f));
        }
    }
    __syncthreads();
    for (int i = tid; i < m; i += 512) {
        unsigned long long pk = eL[i];
        int s = (int)(pk & 0x1FFFF);
        int ld = (int)((pk >> 17) & (NPB - 1));
        int pos = rowL[ld] + (int)atomicAdd(&fillL[ld], 1u);
        csr[pos] = (unsigned long long)(unsigned)s | (pk & 0xFFFFFFFF00000000ull);
    }
}

// ==================== scale h0 (bf16) by dinv -> g0 in place ====================
__global__ __launch_bounds__(256) void k_scale(unsigned short* __restrict__ h0,
                                               const float* __restrict__ dinv, int n) {
    int i = blockIdx.x * 256 + threadIdx.x;   // one thread per 4 channels
    if (i >= n * 16) return;
    int node = i >> 4;
    float sc = dinv[node];
    ushort4 u = *(ushort4*)&h0[(size_t)i * 4];
    u = make_ushort4(f2b(b2f(u.x) * sc), f2b(b2f(u.y) * sc),
                     f2b(b2f(u.z) * sc), f2b(b2f(u.w) * sc));
    *(ushort4*)&h0[(size_t)i * 4] = u;
}

// -------------------- prop1: gather g0, epilogue writes q = dinv*relu(dinv*acc + b1) --------
__global__ __launch_bounds__(256) void k_prop1(const unsigned short* __restrict__ g,
                                               const int2* __restrict__ csr,
                                               const int2* __restrict__ rowcnt,
                                               const float* __restrict__ dinv,
                                               const float* __restrict__ bias0,
                                               unsigned short* __restrict__ outq, int n) {
    int node = blockIdx.x * 4 + (threadIdx.x >> 6);
    if (node >= n) return;
    int lane = threadIdx.x & 63;
    int q = lane >> 4;
    int t = lane & 15;
    float a0 = 0.f, a1 = 0.f, a2 = 0.f, a3 = 0.f;
    int2 rc = rowcnt[node];
    const int2* ep = csr + rc.x;
    int m = rc.y;
    for (int e = 0; e < m; e += 8) {
        int e1 = e + q, e2 = e + 4 + q;
        if (e1 < m) {
            int2 p = ep[e1];
            uint2 r = *(const uint2*)(g + (size_t)p.x * 64 + t * 4);
            float nm = __int_as_float(p.y);
            a0 = fmaf(b2f_lo(r.x), nm, a0);
            a1 = fmaf(b2f_hi(r.x), nm, a1);
            a2 = fmaf(b2f_lo(r.y), nm, a2);
            a3 = fmaf(b2f_hi(r.y), nm, a3);
        }
        if (e2 < m) {
            int2 p = ep[e2];
            uint2 r = *(const uint2*)(g + (size_t)p.x * 64 + t * 4);
            float nm = __int_as_float(p.y);
            a0 = fmaf(b2f_lo(r.x), nm, a0);
            a1 = fmaf(b2f_hi(r.x), nm, a1);
            a2 = fmaf(b2f_lo(r.y), nm, a2);
            a3 = fmaf(b2f_hi(r.y), nm, a3);
        }
    }
    a0 += __shfl_xor(a0, 16); a0 += __shfl_xor(a0, 32);
    a1 += __shfl_xor(a1, 16); a1 += __shfl_xor(a1, 32);
    a2 += __shfl_xor(a2, 16); a2 += __shfl_xor(a2, 32);
    a3 += __shfl_xor(a3, 16); a3 += __shfl_xor(a3, 32);
    if (q != 0) return;
    uint2 sr = *(const uint2*)(g + (size_t)node * 64 + t * 4);
    a0 += b2f_lo(sr.x); a1 += b2f_hi(sr.x);
    a2 += b2f_lo(sr.y); a3 += b2f_hi(sr.y);
    float di = dinv[node];
    float4 bb = ld4(bias0 + t * 4);
    a0 = fmaxf(fmaf(a0, di, bb.x), 0.f) * di;
    a1 = fmaxf(fmaf(a1, di, bb.y), 0.f) * di;
    a2 = fmaxf(fmaf(a2, di, bb.z), 0.f) * di;
    a3 = fmaxf(fmaf(a3, di, bb.w), 0.f) * di;
    ushort4 u = make_ushort4(f2b(a0), f2b(a1), f2b(a2), f2b(a3));
    *(ushort4*)(outq + (size_t)node * 64 + t * 4) = u;
}

// -------------------- prop2 fused with layer-2 GEMM --------------------
// Block = 64 nodes (4 waves x 16 sequential gathers). Wave gathers node's A = q[d] + sum w*q[s],
// q0 lanes stage dinv_d*A into LDS (stride 68 -> 2-way free). Then 64x64x64 tile GEMM vs fused
// [Wmu|Wlv] and store mu/lv fp32 with bias.
__global__ __launch_bounds__(256) void k_prop2g(const unsigned short* __restrict__ qv,
                                                const int2* __restrict__ csr,
                                                const int2* __restrict__ rowcnt,
                                                const float* __restrict__ dinv,
                                                const float* __restrict__ Wmu,
                                                const float* __restrict__ Wlv,
                                                const float* __restrict__ bmu,
                                                const float* __restrict__ blv,
                                                float* __restrict__ outp, int n) {
    __shared__ float accL[64 * 68];   // 17.4 KB
    __shared__ float Ws[64 * 64];     // 16 KB fused [Wmu|Wlv]
    int tid = threadIdx.x;
    for (int j = tid; j < 1024; j += 256) {
        int k = (j * 4) >> 6;
        int c = (j * 4) & 63;
        float4 v = (c < 32) ? ld4(Wmu + k * 32 + c) : ld4(Wlv + k * 32 + (c - 32));
        *(float4*)&Ws[j * 4] = v;
    }
    int wv = tid >> 6, lane = tid & 63;
    int q = lane >> 4, t = lane & 15;
    int node0 = blockIdx.x * 64;
    for (int i = 0; i < 16; i++) {
        int node = node0 + wv * 16 + i;
        float a0 = 0.f, a1 = 0.f, a2 = 0.f, a3 = 0.f;
        if (node < n) {
            int2 rc = rowcnt[node];
            const int2* ep = csr + rc.x;
            int m = rc.y;
            for (int e = 0; e < m; e += 8) {
                int e1 = e + q, e2 = e + 4 + q;
                if (e1 < m) {
                    int2 p = ep[e1];
                    uint2 r = *(const uint2*)(qv + (size_t)p.x * 64 + t * 4);
                    float nm = __int_as_float(p.y);
                    a0 = fmaf(b2f_lo(r.x), nm, a0);
                    a1 = fmaf(b2f_hi(r.x), nm, a1);
                    a2 = fmaf(b2f_lo(r.y), nm, a2);
                    a3 = fmaf(b2f_hi(r.y), nm, a3);
                }
                if (e2 < m) {
                    int2 p = ep[e2];
                    uint2 r = *(const uint2*)(qv + (size_t)p.x * 64 + t * 4);
                    float nm = __int_as_float(p.y);
                    a0 = fmaf(b2f_lo(r.x), nm, a0);
                    a1 = fmaf(b2f_hi(r.x), nm, a1);
                    a2 = fmaf(b2f_lo(r.y), nm, a2);
                    a3 = fmaf(b2f_hi(r.y), nm, a3);
                }
            }
            if (q == 0) {   // self-loop once, pre-reduce
                uint2 sr = *(const uint2*)(qv + (size_t)node * 64 + t * 4);
                a0 += b2f_lo(sr.x); a1 += b2f_hi(sr.x);
                a2 += b2f_lo(sr.y); a3 += b2f_hi(sr.y);
            }
        }
        a0 += __shfl_xor(a0, 16); a0 += __shfl_xor(a0, 32);
        a1 += __shfl_xor(a1, 16); a1 += __shfl_xor(a1, 32);
        a2 += __shfl_xor(a2, 16); a2 += __shfl_xor(a2, 32);
        a3 += __shfl_xor(a3, 16); a3 += __shfl_xor(a3, 32);
        if (q == 0) {
            float di = (node < n) ? dinv[node] : 0.f;
            float4 v = make_float4(a0 * di, a1 * di, a2 * di, a3 * di);
            *(float4*)&accL[(wv * 16 + i) * 68 + t * 4] = v;
        }
    }
    __syncthreads();
    // 64x64x64 tile GEMM: out[r][c] = accL[r][:] . Ws[:][c]
    int c0 = (tid & 15) * 4;
    int r0 = (tid >> 4) * 4;
    float4 acc[4] = {};
    #pragma unroll 4
    for (int kk = 0; kk < 64; kk += 4) {
        float4 w0 = ld4(&Ws[(kk + 0) * 64 + c0]);
        float4 w1 = ld4(&Ws[(kk + 1) * 64 + c0]);
        float4 w2 = ld4(&Ws[(kk + 2) * 64 + c0]);
        float4 w3 = ld4(&Ws[(kk + 3) * 64 + c0]);
        #pragma unroll
        for (int i = 0; i < 4; i++) {
            float4 a = ld4(&accL[(r0 + i) * 68 + kk]);
            acc[i].x = fmaf(a.x, w0.x, fmaf(a.y, w1.x, fmaf(a.z, w2.x, fmaf(a.w, w3.x, acc[i].x))));
            acc[i].y = fmaf(a.x, w0.y, fmaf(a.y, w1.y, fmaf(a.z, w2.y, fmaf(a.w, w3.y, acc[i].y))));
            acc[i].z = fmaf(a.x, w0.z, fmaf(a.y, w1.z, fmaf(a.z, w2.z, fmaf(a.w, w3.z, acc[i].z))));
            acc[i].w = fmaf(a.x, w0.w, fmaf(a.y, w1.w, fmaf(a.z, w2.w, fmaf(a.w, w3.w, acc[i].w))));
        }
    }
    float4 bb = (c0 < 32) ? ld4(bmu + c0) : ld4(blv + c0 - 32);
    #pragma unroll
    for (int i = 0; i < 4; i++) {
        int row = node0 + r0 + i;
        if (row < n) {
            float4 v = make_float4(acc[i].x + bb.x, acc[i].y + bb.y,
                                   acc[i].z + bb.z, acc[i].w + bb.w);
            if (c0 < 32) *(float4*)&outp[(size_t)row * 32 + c0] = v;
            else         *(float4*)&outp[(size_t)n * 32 + (size_t)row * 32 + (c0 - 32)] = v;
        }
    }
}

// -------------------- launch --------------------
extern "C" void kernel_launch(void* const* d_in, const int* in_sizes, int n_in,
                              void* d_out, int out_size, void* d_ws, size_t ws_size,
                              hipStream_t stream) {
    const float* x   = (const float*)d_in[0];
    const int*   ei  = (const int*)d_in[1];   // [2, E]
    const float* ew  = (const float*)d_in[2];
    const float* W1  = (const float*)d_in[3];
    const float* b1  = (const float*)d_in[4];
    const float* Wmu = (const float*)d_in[5];
    const float* bmu = (const float*)d_in[6];
    const float* Wlv = (const float*)d_in[7];
    const float* blv = (const float*)d_in[8];
    float* outp = (float*)d_out;

    const int n = in_sizes[0] / 128;
    const int E = in_sizes[2];
    const int* src = ei;
    const int* dst = ei + E;
    const int NB = (n + NPB - 1) / NPB;            // bins of 256 nodes

    // workspace layout
    size_t o = 0;
    auto alloc = [&](size_t bytes) { void* p = (char*)d_ws + o; o += (bytes + 511) & ~(size_t)511; return p; };
    int*   bin_cnt  = (int*)alloc((size_t)NB * 4);                 // memset 0
    int2*  rowcnt   = (int2*)alloc((size_t)n * 8);
    float* dinv     = (float*)alloc((size_t)n * 4);
    unsigned long long* csr  = (unsigned long long*)alloc((size_t)E * 8);
    unsigned long long* ebuf = (unsigned long long*)alloc((size_t)NB * CAPE * 8);
    unsigned short* g0 = (unsigned short*)alloc((size_t)n * 64 * 2);   // bf16 (h0 then g0)
    unsigned short* qb = (unsigned short*)alloc((size_t)n * 64 * 2);   // bf16 q

    const int gb = (n + 63) / 64;                  // gemm blocks
    const int bb = (E + 4095) / 4096;              // bin blocks

    hipMemsetAsync(bin_cnt, 0, (size_t)NB * 4, stream);
    k_fused1<<<gb + bb, 256, 0, stream>>>(x, W1, g0, src, dst, ew, bin_cnt, ebuf, n, E, gb, NB);
    k_csr_build<<<NB, 512, 0, stream>>>(ebuf, bin_cnt, rowcnt, dinv, csr, n);
    k_scale<<<(n * 16 + 255) / 256, 256, 0, stream>>>(g0, dinv, n);
    k_prop1<<<(n + 3) / 4, 256, 0, stream>>>(g0, (const int2*)csr, rowcnt, dinv, b1, qb, n);
    k_prop2g<<<gb, 256, 0, stream>>>(qb, (const int2*)csr, rowcnt, dinv,
                                     Wmu, Wlv, bmu, blv, outp, n);
}

// Round 11
// 330.128 us; speedup vs baseline: 1.1307x; 1.1307x over previous
//
#include <hip/hip_runtime.h>

// -------------------- helpers --------------------
static __device__ __forceinline__ float4 ld4(const float* p) { return *(const float4*)p; }
static __device__ __forceinline__ float b2f(unsigned short u) {
    return __uint_as_float((unsigned)u << 16);
}
static __device__ __forceinline__ float b2f_lo(unsigned u) { return __uint_as_float(u << 16); }
static __device__ __forceinline__ float b2f_hi(unsigned u) { return __uint_as_float(u & 0xFFFF0000u); }
static __device__ __forceinline__ unsigned short f2b(float f) {   // round-to-nearest-even
    unsigned x = __float_as_uint(f);
    return (unsigned short)((x + 0x7FFFu + ((x >> 16) & 1u)) >> 16);
}

#define NPB 256              // nodes per bin (pow2: ld = d & 255, bin = d >> 8)
#define CAPE 5120            // per-bin edge capacity (mean ~4092, wide slack)

// math: layer1  q[d] = dinv_d * relu( dinv_d*(g0[d] + sum_e w_e*g0[s]) + b1 ),  g0 = dinv (.) (x@W1)
//       layer2  [mu|lv][d] = ( dinv_d*(q[d] + sum_e w_e*q[s]) ) @ [Wmu|Wlv] + [bmu|blv]
// CSR stores (src, raw ew).

// ==================== fused kernel 1: gemm1 (x@W1 -> h0, unscaled) + edge binning ============
__global__ __launch_bounds__(256) void k_fused1(const float* __restrict__ A,
                                                const float* __restrict__ W0,
                                                unsigned short* __restrict__ hout,
                                                const int* __restrict__ src,
                                                const int* __restrict__ dst,
                                                const float* __restrict__ ew,
                                                int* __restrict__ bin_cnt,
                                                unsigned long long* __restrict__ ebuf,
                                                int n, int E, int gb, int NB) {
    __shared__ float Ws[64 * 64];     // 16 KB
    __shared__ float Xs[64 * 64];     // 16 KB
    __shared__ int hist[512];
    __shared__ int hbase[512];
    int tid = threadIdx.x;

    if ((int)blockIdx.x < gb) {
        int row0 = blockIdx.x * 64;
        int c0 = (tid & 15) * 4;
        int r0 = (tid >> 4) * 4;
        float4 acc[4] = {};
        #pragma unroll
        for (int p = 0; p < 2; p++) {
            for (int j = tid; j < 1024; j += 256)
                *(float4*)&Ws[j * 4] = ld4(W0 + p * 4096 + j * 4);
            for (int j = tid; j < 1024; j += 256) {
                int r = j >> 4, kc = j & 15;
                int grow = row0 + r;
                float4 v = make_float4(0.f, 0.f, 0.f, 0.f);
                if (grow < n) v = ld4(A + (size_t)grow * 128 + p * 64 + kc * 4);
                *(float4*)&Xs[r * 64 + kc * 4] = v;
            }
            __syncthreads();
            #pragma unroll 4
            for (int kk = 0; kk < 64; kk += 4) {
                float4 w0 = ld4(&Ws[(kk + 0) * 64 + c0]);
                float4 w1 = ld4(&Ws[(kk + 1) * 64 + c0]);
                float4 w2 = ld4(&Ws[(kk + 2) * 64 + c0]);
                float4 w3 = ld4(&Ws[(kk + 3) * 64 + c0]);
                #pragma unroll
                for (int i = 0; i < 4; i++) {
                    float4 a = ld4(&Xs[(r0 + i) * 64 + kk]);
                    acc[i].x = fmaf(a.x, w0.x, fmaf(a.y, w1.x, fmaf(a.z, w2.x, fmaf(a.w, w3.x, acc[i].x))));
                    acc[i].y = fmaf(a.x, w0.y, fmaf(a.y, w1.y, fmaf(a.z, w2.y, fmaf(a.w, w3.y, acc[i].y))));
                    acc[i].z = fmaf(a.x, w0.z, fmaf(a.y, w1.z, fmaf(a.z, w2.z, fmaf(a.w, w3.z, acc[i].z))));
                    acc[i].w = fmaf(a.x, w0.w, fmaf(a.y, w1.w, fmaf(a.z, w2.w, fmaf(a.w, w3.w, acc[i].w))));
                }
            }
            __syncthreads();
        }
        #pragma unroll
        for (int i = 0; i < 4; i++) {
            int grow = row0 + r0 + i;
            if (grow < n) {
                ushort4 u = make_ushort4(f2b(acc[i].x), f2b(acc[i].y), f2b(acc[i].z), f2b(acc[i].w));
                *(ushort4*)&hout[(size_t)grow * 64 + c0] = u;
            }
        }
    } else {
        for (int j = tid; j < NB; j += 256) hist[j] = 0;
        __syncthreads();
        int e0 = ((int)blockIdx.x - gb) * 4096;
        unsigned long long pk[16]; int bb[16]; int loc[16];
        #pragma unroll
        for (int j = 0; j < 16; j++) {
            int e = e0 + j * 256 + tid;
            if (e < E) {
                int s = src[e];
                int d = dst[e];
                float w = ew[e];
                bb[j] = d >> 8;
                pk[j] = ((unsigned long long)__float_as_uint(w) << 32) |
                        (unsigned)((d & (NPB - 1)) << 17) | (unsigned)s;
                loc[j] = atomicAdd(&hist[bb[j]], 1);
            } else bb[j] = -1;
        }
        __syncthreads();
        for (int j = tid; j < NB; j += 256) hbase[j] = atomicAdd(&bin_cnt[j], hist[j]);
        __syncthreads();
        #pragma unroll
        for (int j = 0; j < 16; j++) {
            if (bb[j] >= 0)
                ebuf[(size_t)bb[j] * CAPE + hbase[bb[j]] + loc[j]] = pk[j];
        }
    }
}

// ==================== pass 2: per-bin count+scan+scatter + g0 scale tail ====================
__global__ __launch_bounds__(512) void k_csr_build(const unsigned long long* __restrict__ ebuf,
                                                   const int* __restrict__ bin_cnt,
                                                   int2* __restrict__ rowcnt,
                                                   float* __restrict__ dinv,
                                                   unsigned long long* __restrict__ csr,
                                                   unsigned short* __restrict__ g0,
                                                   int n) {
    __shared__ unsigned long long eL[CAPE];   // 40 KB
    __shared__ unsigned cntL[NPB];
    __shared__ unsigned ewsL[NPB];
    __shared__ unsigned fillL[NPB];
    __shared__ int scanL[512];
    __shared__ int rowL[NPB];
    __shared__ float diL[NPB];
    __shared__ int binbase_s;
    int b = blockIdx.x;
    int tid = threadIdx.x;
    if (tid < NPB) { cntL[tid] = 0; ewsL[tid] = 0; fillL[tid] = 0; }
    scanL[tid] = (tid < b) ? bin_cnt[tid] : 0;
    __syncthreads();
    int m = bin_cnt[b];
    const unsigned long long* eb = ebuf + (size_t)b * CAPE;
    for (int i = tid; i < m; i += 512) {
        unsigned long long pk = eb[i];
        eL[i] = pk;
        int ld = (int)((pk >> 17) & (NPB - 1));
        float w = __uint_as_float((unsigned)(pk >> 32));
        atomicAdd(&cntL[ld], 1u);
        atomicAdd(&ewsL[ld], (unsigned)(w * 16777216.0f));   // 2^24 fixed point
    }
    __syncthreads();
    #pragma unroll
    for (int off = 256; off > 0; off >>= 1) {
        if (tid < off) scanL[tid] += scanL[tid + off];
        __syncthreads();
    }
    if (tid == 0) binbase_s = scanL[0];
    __syncthreads();
    int v = (tid < NPB) ? (int)cntL[tid] : 0;
    scanL[tid] = v;
    __syncthreads();
    #pragma unroll
    for (int off = 1; off < 512; off <<= 1) {
        int t = (tid >= off) ? scanL[tid - off] : 0;
        __syncthreads();
        scanL[tid] += t;
        __syncthreads();
    }
    if (tid < NPB) {
        int rp = binbase_s + scanL[tid] - v;
        rowL[tid] = rp;
        float di = rsqrtf(1.0f + (float)ewsL[tid] * (1.0f / 16777216.0f));
        diL[tid] = di;
        int node = b * NPB + tid;
        if (node < n) {
            rowcnt[node] = make_int2(rp, v);
            dinv[node] = di;
        }
    }
    __syncthreads();
    for (int i = tid; i < m; i += 512) {
        unsigned long long pk = eL[i];
        int s = (int)(pk & 0x1FFFF);
        int ld = (int)((pk >> 17) & (NPB - 1));
        int pos = rowL[ld] + (int)atomicAdd(&fillL[ld], 1u);
        csr[pos] = (unsigned long long)(unsigned)s | (pk & 0xFFFFFFFF00000000ull);
    }
    // ---- scale tail: g0 rows of this bin's nodes *= dinv (ushort4 granularity) ----
    int nbeg = b * NPB;
    for (int idx = tid; idx < NPB * 16; idx += 512) {
        int nl = idx >> 4;
        int node = nbeg + nl;
        if (node >= n) break;
        float sc = diL[nl];
        ushort4 u = *(ushort4*)&g0[((size_t)node * 16 + (idx & 15)) * 4];
        u = make_ushort4(f2b(b2f(u.x) * sc), f2b(b2f(u.y) * sc),
                         f2b(b2f(u.z) * sc), f2b(b2f(u.w) * sc));
        *(ushort4*)&g0[((size_t)node * 16 + (idx & 15)) * 4] = u;
    }
}

// -------------------- prop1: gather g0, epilogue writes q = dinv*relu(dinv*acc + b1) --------
__global__ __launch_bounds__(256) void k_prop1(const unsigned short* __restrict__ g,
                                               const int2* __restrict__ csr,
                                               const int2* __restrict__ rowcnt,
                                               const float* __restrict__ dinv,
                                               const float* __restrict__ bias0,
                                               unsigned short* __restrict__ outq, int n) {
    int node = blockIdx.x * 4 + (threadIdx.x >> 6);
    if (node >= n) return;
    int lane = threadIdx.x & 63;
    int q = lane >> 4;
    int t = lane & 15;
    float a0 = 0.f, a1 = 0.f, a2 = 0.f, a3 = 0.f;
    int2 rc = rowcnt[node];
    const int2* ep = csr + rc.x;
    int m = rc.y;
    for (int e = 0; e < m; e += 8) {
        int e1 = e + q, e2 = e + 4 + q;
        if (e1 < m) {
            int2 p = ep[e1];
            uint2 r = *(const uint2*)(g + (size_t)p.x * 64 + t * 4);
            float nm = __int_as_float(p.y);
            a0 = fmaf(b2f_lo(r.x), nm, a0);
            a1 = fmaf(b2f_hi(r.x), nm, a1);
            a2 = fmaf(b2f_lo(r.y), nm, a2);
            a3 = fmaf(b2f_hi(r.y), nm, a3);
        }
        if (e2 < m) {
            int2 p = ep[e2];
            uint2 r = *(const uint2*)(g + (size_t)p.x * 64 + t * 4);
            float nm = __int_as_float(p.y);
            a0 = fmaf(b2f_lo(r.x), nm, a0);
            a1 = fmaf(b2f_hi(r.x), nm, a1);
            a2 = fmaf(b2f_lo(r.y), nm, a2);
            a3 = fmaf(b2f_hi(r.y), nm, a3);
        }
    }
    a0 += __shfl_xor(a0, 16); a0 += __shfl_xor(a0, 32);
    a1 += __shfl_xor(a1, 16); a1 += __shfl_xor(a1, 32);
    a2 += __shfl_xor(a2, 16); a2 += __shfl_xor(a2, 32);
    a3 += __shfl_xor(a3, 16); a3 += __shfl_xor(a3, 32);
    if (q != 0) return;
    uint2 sr = *(const uint2*)(g + (size_t)node * 64 + t * 4);
    a0 += b2f_lo(sr.x); a1 += b2f_hi(sr.x);
    a2 += b2f_lo(sr.y); a3 += b2f_hi(sr.y);
    float di = dinv[node];
    float4 bb = ld4(bias0 + t * 4);
    a0 = fmaxf(fmaf(a0, di, bb.x), 0.f) * di;
    a1 = fmaxf(fmaf(a1, di, bb.y), 0.f) * di;
    a2 = fmaxf(fmaf(a2, di, bb.z), 0.f) * di;
    a3 = fmaxf(fmaf(a3, di, bb.w), 0.f) * di;
    ushort4 u = make_ushort4(f2b(a0), f2b(a1), f2b(a2), f2b(a3));
    *(ushort4*)(outq + (size_t)node * 64 + t * 4) = u;
}

// -------------------- prop2 fused with layer-2 GEMM (occupancy-preserving shape) ----------
// Block = 16 nodes (4 waves x 4 sequential gathers). LDS ~20.7 KB -> 7 blocks/CU, 28 waves/CU.
// Wave gathers A = q[d] + sum w*q[s]; q0 lanes stage dinv_d*A into accL (stride 68). Then a
// 16x64x64 tile GEMM vs fused [Wmu|Wlv]: one output quad per thread.
__global__ __launch_bounds__(256) void k_prop2g(const unsigned short* __restrict__ qv,
                                                const int2* __restrict__ csr,
                                                const int2* __restrict__ rowcnt,
                                                const float* __restrict__ dinv,
                                                const float* __restrict__ Wmu,
                                                const float* __restrict__ Wlv,
                                                const float* __restrict__ bmu,
                                                const float* __restrict__ blv,
                                                float* __restrict__ outp, int n) {
    __shared__ float accL[16 * 68];   // 4.35 KB
    __shared__ float Ws[64 * 64];     // 16 KB fused [Wmu|Wlv]
    int tid = threadIdx.x;
    for (int j = tid; j < 1024; j += 256) {
        int k = (j * 4) >> 6;
        int c = (j * 4) & 63;
        float4 v = (c < 32) ? ld4(Wmu + k * 32 + c) : ld4(Wlv + k * 32 + (c - 32));
        *(float4*)&Ws[j * 4] = v;
    }
    int wv = tid >> 6, lane = tid & 63;
    int q = lane >> 4, t = lane & 15;
    int node0 = blockIdx.x * 16;
    #pragma unroll
    for (int i = 0; i < 4; i++) {
        int node = node0 + wv * 4 + i;
        float a0 = 0.f, a1 = 0.f, a2 = 0.f, a3 = 0.f;
        if (node < n) {
            int2 rc = rowcnt[node];
            const int2* ep = csr + rc.x;
            int m = rc.y;
            for (int e = 0; e < m; e += 8) {
                int e1 = e + q, e2 = e + 4 + q;
                if (e1 < m) {
                    int2 p = ep[e1];
                    uint2 r = *(const uint2*)(qv + (size_t)p.x * 64 + t * 4);
                    float nm = __int_as_float(p.y);
                    a0 = fmaf(b2f_lo(r.x), nm, a0);
                    a1 = fmaf(b2f_hi(r.x), nm, a1);
                    a2 = fmaf(b2f_lo(r.y), nm, a2);
                    a3 = fmaf(b2f_hi(r.y), nm, a3);
                }
                if (e2 < m) {
                    int2 p = ep[e2];
                    uint2 r = *(const uint2*)(qv + (size_t)p.x * 64 + t * 4);
                    float nm = __int_as_float(p.y);
                    a0 = fmaf(b2f_lo(r.x), nm, a0);
                    a1 = fmaf(b2f_hi(r.x), nm, a1);
                    a2 = fmaf(b2f_lo(r.y), nm, a2);
                    a3 = fmaf(b2f_hi(r.y), nm, a3);
                }
            }
            if (q == 0) {   // self-loop once, pre-reduce
                uint2 sr = *(const uint2*)(qv + (size_t)node * 64 + t * 4);
                a0 += b2f_lo(sr.x); a1 += b2f_hi(sr.x);
                a2 += b2f_lo(sr.y); a3 += b2f_hi(sr.y);
            }
        }
        a0 += __shfl_xor(a0, 16); a0 += __shfl_xor(a0, 32);
        a1 += __shfl_xor(a1, 16); a1 += __shfl_xor(a1, 32);
        a2 += __shfl_xor(a2, 16); a2 += __shfl_xor(a2, 32);
        a3 += __shfl_xor(a3, 16); a3 += __shfl_xor(a3, 32);
        if (q == 0) {
            float di = (node < n) ? dinv[node] : 0.f;
            float4 v = make_float4(a0 * di, a1 * di, a2 * di, a3 * di);
            *(float4*)&accL[(wv * 4 + i) * 68 + t * 4] = v;
        }
    }
    __syncthreads();
    // 16x64x64 tile GEMM: thread (r = tid>>4, c0 = (tid&15)*4)
    int r = tid >> 4;
    int c0 = (tid & 15) * 4;
    float4 acc = make_float4(0.f, 0.f, 0.f, 0.f);
    #pragma unroll 4
    for (int kk = 0; kk < 64; kk += 4) {
        float4 a = ld4(&accL[r * 68 + kk]);
        float4 w0 = ld4(&Ws[(kk + 0) * 64 + c0]);
        float4 w1 = ld4(&Ws[(kk + 1) * 64 + c0]);
        float4 w2 = ld4(&Ws[(kk + 2) * 64 + c0]);
        float4 w3 = ld4(&Ws[(kk + 3) * 64 + c0]);
        acc.x = fmaf(a.x, w0.x, fmaf(a.y, w1.x, fmaf(a.z, w2.x, fmaf(a.w, w3.x, acc.x))));
        acc.y = fmaf(a.x, w0.y, fmaf(a.y, w1.y, fmaf(a.z, w2.y, fmaf(a.w, w3.y, acc.y))));
        acc.z = fmaf(a.x, w0.z, fmaf(a.y, w1.z, fmaf(a.z, w2.z, fmaf(a.w, w3.z, acc.z))));
        acc.w = fmaf(a.x, w0.w, fmaf(a.y, w1.w, fmaf(a.z, w2.w, fmaf(a.w, w3.w, acc.w))));
    }
    int row = node0 + r;
    if (row < n) {
        float4 bb = (c0 < 32) ? ld4(bmu + c0) : ld4(blv + c0 - 32);
        float4 v = make_float4(acc.x + bb.x, acc.y + bb.y, acc.z + bb.z, acc.w + bb.w);
        if (c0 < 32) *(float4*)&outp[(size_t)row * 32 + c0] = v;
        else         *(float4*)&outp[(size_t)n * 32 + (size_t)row * 32 + (c0 - 32)] = v;
    }
}

// -------------------- launch --------------------
extern "C" void kernel_launch(void* const* d_in, const int* in_sizes, int n_in,
                              void* d_out, int out_size, void* d_ws, size_t ws_size,
                              hipStream_t stream) {
    const float* x   = (const float*)d_in[0];
    const int*   ei  = (const int*)d_in[1];   // [2, E]
    const float* ew  = (const float*)d_in[2];
    const float* W1  = (const float*)d_in[3];
    const float* b1  = (const float*)d_in[4];
    const float* Wmu = (const float*)d_in[5];
    const float* bmu = (const float*)d_in[6];
    const float* Wlv = (const float*)d_in[7];
    const float* blv = (const float*)d_in[8];
    float* outp = (float*)d_out;

    const int n = in_sizes[0] / 128;
    const int E = in_sizes[2];
    const int* src = ei;
    const int* dst = ei + E;
    const int NB = (n + NPB - 1) / NPB;            // bins of 256 nodes

    // workspace layout
    size_t o = 0;
    auto alloc = [&](size_t bytes) { void* p = (char*)d_ws + o; o += (bytes + 511) & ~(size_t)511; return p; };
    int*   bin_cnt  = (int*)alloc((size_t)NB * 4);                 // memset 0
    int2*  rowcnt   = (int2*)alloc((size_t)n * 8);
    float* dinv     = (float*)alloc((size_t)n * 4);
    unsigned long long* csr  = (unsigned long long*)alloc((size_t)E * 8);
    unsigned long long* ebuf = (unsigned long long*)alloc((size_t)NB * CAPE * 8);
    unsigned short* g0 = (unsigned short*)alloc((size_t)n * 64 * 2);   // bf16 (h0 then g0)
    unsigned short* qb = (unsigned short*)alloc((size_t)n * 64 * 2);   // bf16 q

    const int gb = (n + 63) / 64;                  // gemm blocks
    const int bb = (E + 4095) / 4096;              // bin blocks

    hipMemsetAsync(bin_cnt, 0, (size_t)NB * 4, stream);
    k_fused1<<<gb + bb, 256, 0, stream>>>(x, W1, g0, src, dst, ew, bin_cnt, ebuf, n, E, gb, NB);
    k_csr_build<<<NB, 512, 0, stream>>>(ebuf, bin_cnt, rowcnt, dinv, csr, g0, n);
    k_prop1<<<(n + 3) / 4, 256, 0, stream>>>(g0, (const int2*)csr, rowcnt, dinv, b1, qb, n);
    k_prop2g<<<(n + 15) / 16, 256, 0, stream>>>(qb, (const int2*)csr, rowcnt, dinv,
                                                Wmu, Wlv, bmu, blv, outp, n);
}